// Round 7
// baseline (47.717 us; speedup 1.0000x reference)
//
#include <hip/hip_runtime.h>

// Causal depthwise Conv1d: x[B,L,C] f32, weight[C,1,K] f32, bias[C] f32.
// y[b,l,c] = bias[c] + sum_k w[c,k] * x[b, l-6+k, c], zero-pad left.
// B=8, L=4096, C=1024, K=7.
//
// R7: occupancy experiment. waves/CU = 512/LT, halo overhead = 6/LT.
// LT=32 -> 1024 blocks, 16 waves/CU (2x R6) at +12 MB issued halo bytes.
// Forced PF=3 load pipeline (sched_barrier fences), nt stores, XCD remap.

typedef float f32x4 __attribute__((ext_vector_type(4)));

constexpr int Lc = 4096;
constexpr int C4 = 256;   // C/4 float4 lanes
constexpr int K  = 7;
constexpr int LT = 32;    // L positions per block
constexpr int NB = LT / 4;
constexpr int PF = 3;     // prefetch distance in batches

__global__ __launch_bounds__(256, 4) void dwconv_kernel(
    const f32x4* __restrict__ x, const float* __restrict__ w,
    const float* __restrict__ bias, f32x4* __restrict__ y) {
  const int c4 = threadIdx.x;                      // 0..255 -> channels c4*4..+3
  const int bx = blockIdx.x;                       // 0..127
  const int tile = ((bx & 7) << 4) | (bx >> 3);    // XCD-chunked bijective remap (8x16)
  const int l0 = tile * LT;
  const int b  = blockIdx.y;
  const int c  = c4 * 4;

  // Weights: 28 contiguous floats at w + c*7 (16B-aligned since c*7*4 = 112*c4).
  float ww[28];  // ww[j*7 + k] = channel (c+j), tap k
  {
    const f32x4* wv = reinterpret_cast<const f32x4*>(w + (size_t)c * K);
#pragma unroll
    for (int i = 0; i < 7; ++i) {
      f32x4 t = wv[i];
      ww[i * 4 + 0] = t.x; ww[i * 4 + 1] = t.y;
      ww[i * 4 + 2] = t.z; ww[i * 4 + 3] = t.w;
    }
  }
  const f32x4 bv = reinterpret_cast<const f32x4*>(bias)[c4];

  const f32x4* xb = x + (size_t)b * Lc * C4 + c4;
  f32x4*       yb = y + (size_t)b * Lc * C4 + c4;

  // Register window: v[i] = x[l0 - 6 + i], i = 0..LT+5.
  f32x4 v[LT + 6];
  const f32x4 fz = {0.f, 0.f, 0.f, 0.f};
#pragma unroll
  for (int i = 0; i < 6; ++i) {
    const int l = l0 - 6 + i;
    v[i] = (l >= 0) ? xb[(size_t)l * C4] : fz;
  }
  // Prologue: batches 0..PF-1 (12 loads in flight).
#pragma unroll
  for (int i = 0; i < PF * 4; ++i) {
    v[6 + i] = xb[(size_t)(l0 + i) * C4];
  }
  __builtin_amdgcn_sched_barrier(0);  // prologue loads stay above

#pragma unroll
  for (int jb = 0; jb < NB; ++jb) {
    // Prefetch batch jb+PF (keeps 12 loads outstanding through the compute).
    if (jb + PF < NB) {
#pragma unroll
      for (int i = 0; i < 4; ++i) {
        v[6 + (jb + PF) * 4 + i] = xb[(size_t)(l0 + (jb + PF) * 4 + i) * C4];
      }
    }
    __builtin_amdgcn_sched_barrier(0);  // prefetch may not sink below
    // Compute + store batch jb (waits only for its own batch).
#pragma unroll
    for (int i = 0; i < 4; ++i) {
      const int li = jb * 4 + i;
      f32x4 acc = bv;
#pragma unroll
      for (int k = 0; k < K; ++k) {
        const f32x4 xv = v[li + k];
        acc.x = fmaf(ww[0 * 7 + k], xv.x, acc.x);
        acc.y = fmaf(ww[1 * 7 + k], xv.y, acc.y);
        acc.z = fmaf(ww[2 * 7 + k], xv.z, acc.z);
        acc.w = fmaf(ww[3 * 7 + k], xv.w, acc.w);
      }
      __builtin_nontemporal_store(acc, &yb[(size_t)(l0 + li) * C4]);
    }
    __builtin_amdgcn_sched_barrier(0);  // compute may not float up past prefetch
  }
}

extern "C" void kernel_launch(void* const* d_in, const int* in_sizes, int n_in,
                              void* d_out, int out_size, void* d_ws, size_t ws_size,
                              hipStream_t stream) {
  const f32x4* x    = (const f32x4*)d_in[0];
  const float* w    = (const float*)d_in[1];
  const float* bias = (const float*)d_in[2];
  f32x4*       y    = (f32x4*)d_out;

  const int B = 8;
  dim3 grid(Lc / LT, B, 1);   // 128 x 8 = 1024 blocks (4 per CU)
  dim3 block(C4, 1, 1);
  dwconv_kernel<<<grid, block, 0, stream>>>(x, w, bias, y);
}

// Round 8
// 44.894 us; speedup vs baseline: 1.0629x; 1.0629x over previous
//
#include <hip/hip_runtime.h>

// Causal depthwise Conv1d: x[B,L,C] f32, weight[C,1,K] f32, bias[C] f32.
// y[b,l,c] = bias[c] + sum_k w[c,k] * x[b, l-6+k, c], zero-pad left.
// B=8, L=4096, C=1024, K=7. Bytes-bound: time ~ issued vector bytes / ~6.6 TB/s
// (fit across R1/R2/R6/R7; occupancy 16->29% made no difference).
//
// R8: LT=128 -> 256 blocks (1/CU), minimizes halo (6/128) + weight re-reads.
// Issued bytes 291->276 MB. PF=4-deep forced load pipeline (fences) covers
// latency at 4 waves/CU. One full batch per XCD (halo L2 locality).

typedef float f32x4 __attribute__((ext_vector_type(4)));

constexpr int Lc = 4096;
constexpr int C4 = 256;   // C/4 float4 lanes
constexpr int K  = 7;
constexpr int LT = 128;   // L positions per block
constexpr int NB = LT / 4;
constexpr int PF = 4;     // prefetch distance in batches (16 outstanding loads)

__global__ __launch_bounds__(256, 1) void dwconv_kernel(
    const f32x4* __restrict__ x, const float* __restrict__ w,
    const float* __restrict__ bias, f32x4* __restrict__ y) {
  const int c4 = threadIdx.x;                       // 0..255 -> channels c4*4..+3
  // Flat block id 0..255; chunked remap: one full batch (32 tiles) per XCD.
  const int flat = blockIdx.x + (int)gridDim.x * blockIdx.y;
  const int remap = (flat & 7) * 32 + (flat >> 3);
  const int b    = remap >> 5;        // batch 0..7 (one per XCD)
  const int tile = remap & 31;        // L-tile 0..31 within batch
  const int l0 = tile * LT;
  const int c  = c4 * 4;

  // Weights: 28 contiguous floats at w + c*7 (16B-aligned since c*7*4 = 112*c4).
  float ww[28];  // ww[j*7 + k] = channel (c+j), tap k
  {
    const f32x4* wv = reinterpret_cast<const f32x4*>(w + (size_t)c * K);
#pragma unroll
    for (int i = 0; i < 7; ++i) {
      f32x4 t = wv[i];
      ww[i * 4 + 0] = t.x; ww[i * 4 + 1] = t.y;
      ww[i * 4 + 2] = t.z; ww[i * 4 + 3] = t.w;
    }
  }
  const f32x4 bv = reinterpret_cast<const f32x4*>(bias)[c4];

  const f32x4* xb = x + (size_t)b * Lc * C4 + c4;
  f32x4*       yb = y + (size_t)b * Lc * C4 + c4;

  // Register window: v[i] = x[l0 - 6 + i]. Absolute indexing, fully unrolled;
  // fences force a PF-batch-deep load pipeline (liveness ~ (6+4*PF) f32x4).
  f32x4 v[LT + 6];
  const f32x4 fz = {0.f, 0.f, 0.f, 0.f};
#pragma unroll
  for (int i = 0; i < 6; ++i) {
    const int l = l0 - 6 + i;
    v[i] = (l >= 0) ? xb[(size_t)l * C4] : fz;
  }
  // Prologue: batches 0..PF-1 in flight.
#pragma unroll
  for (int i = 0; i < PF * 4; ++i) {
    v[6 + i] = xb[(size_t)(l0 + i) * C4];
  }
  __builtin_amdgcn_sched_barrier(0);  // prologue loads stay above

#pragma unroll
  for (int jb = 0; jb < NB; ++jb) {
    // Prefetch batch jb+PF.
    if (jb + PF < NB) {
#pragma unroll
      for (int i = 0; i < 4; ++i) {
        v[6 + (jb + PF) * 4 + i] = xb[(size_t)(l0 + (jb + PF) * 4 + i) * C4];
      }
    }
    __builtin_amdgcn_sched_barrier(0);  // prefetch may not sink below
    // Compute + store batch jb (waits only for its own batch).
#pragma unroll
    for (int i = 0; i < 4; ++i) {
      const int li = jb * 4 + i;
      f32x4 acc = bv;
#pragma unroll
      for (int k = 0; k < K; ++k) {
        const f32x4 xv = v[li + k];
        acc.x = fmaf(ww[0 * 7 + k], xv.x, acc.x);
        acc.y = fmaf(ww[1 * 7 + k], xv.y, acc.y);
        acc.z = fmaf(ww[2 * 7 + k], xv.z, acc.z);
        acc.w = fmaf(ww[3 * 7 + k], xv.w, acc.w);
      }
      __builtin_nontemporal_store(acc, &yb[(size_t)(l0 + li) * C4]);
    }
    __builtin_amdgcn_sched_barrier(0);  // compute may not float up past prefetch
  }
}

extern "C" void kernel_launch(void* const* d_in, const int* in_sizes, int n_in,
                              void* d_out, int out_size, void* d_ws, size_t ws_size,
                              hipStream_t stream) {
  const f32x4* x    = (const f32x4*)d_in[0];
  const float* w    = (const float*)d_in[1];
  const float* bias = (const float*)d_in[2];
  f32x4*       y    = (f32x4*)d_out;

  const int B = 8;
  dim3 grid(Lc / LT, B, 1);   // 32 x 8 = 256 blocks (1 per CU)
  dim3 block(C4, 1, 1);
  dwconv_kernel<<<grid, block, 0, stream>>>(x, w, bias, y);
}